// Round 1
// baseline (732.101 us; speedup 1.0000x reference)
//
#include <hip/hip_runtime.h>
#include <hip/hip_bf16.h>

// ---------------------------------------------------------------------------
// CustomMultiheadAttention on MI355X (gfx950)
//   x = softmax((q Wq^T + bq)(k Wk^T + bk)^T / sqrt(64)) (v Wv^T + bv) Wo^T + bo
// Outputs (concat, fp32): x [4,2048,1024], attn [4,16,2048,2048]
//
// Round-0 strategy: all-fp16 MFMA (v_mfma_f32_16x16x16_f16 — textbook lane
// layouts) with fp32 accumulation. Fused two-pass attention (online max/sum,
// recompute S in pass 2, write normalized attn + PV in one go).
// ---------------------------------------------------------------------------

typedef _Float16 h4 __attribute__((ext_vector_type(4)));
typedef float f4 __attribute__((ext_vector_type(4)));

#define EMBED 1024
#define HEADS 16
#define HD 64
#define BB 4
#define SS 2048
#define MROWS (BB * SS) // 8192

__device__ inline float fexp2(float x) {
  float r;
  asm("v_exp_f32 %0, %1" : "=v"(r) : "v"(x));
  return r;
}

// ---------------- cast fp32 -> fp16 (vectorized) ----------------
__global__ __launch_bounds__(256) void cast_f32_f16(const float* __restrict__ in,
                                                    _Float16* __restrict__ out, int n) {
  int i = (blockIdx.x * 256 + threadIdx.x) * 4;
  if (i < n) {
    float4 v = *reinterpret_cast<const float4*>(in + i);
    h4 o = {(_Float16)v.x, (_Float16)v.y, (_Float16)v.z, (_Float16)v.w};
    *reinterpret_cast<h4*>(out + i) = o;
  }
}

// ---------------- GEMM: out[m][n] = sum_k A[m][k] * W[n][k] + bias[n] -------
// 128x128 tile, BK=64, 4 waves (each 64x64), 16x16x16 f16 MFMA.
// LDS rows padded to 72 halves (144B): 16B-aligned rows, 2-way (free) bank aliasing.
template <int OUTF32>
__global__ __launch_bounds__(256, 2) void gemm_bias(const _Float16* __restrict__ A,
                                                    const _Float16* __restrict__ W,
                                                    const float* __restrict__ bias,
                                                    void* __restrict__ out) {
  __shared__ _Float16 la[128][72];
  __shared__ _Float16 lb[128][72];
  const int t = threadIdx.x;
  const int lane = t & 63;
  const int w = t >> 6;
  const int g = lane >> 4, r16 = lane & 15;
  const int wr = (w >> 1) * 64, wc = (w & 1) * 64;
  const int m0 = blockIdx.x * 128, n0 = blockIdx.y * 128;

  f4 acc[4][4] = {};

  for (int kt = 0; kt < EMBED; kt += 64) {
    // stage A and W tiles: 1024 chunks of 16B each tile, 4 per thread
#pragma unroll
    for (int it = 0; it < 4; it++) {
      int c = t + it * 256;
      int row = c >> 3, col8 = (c & 7) * 8;
      *reinterpret_cast<float4*>(&la[row][col8]) =
          *reinterpret_cast<const float4*>(A + (size_t)(m0 + row) * EMBED + kt + col8);
      *reinterpret_cast<float4*>(&lb[row][col8]) =
          *reinterpret_cast<const float4*>(W + (size_t)(n0 + row) * EMBED + kt + col8);
    }
    __syncthreads();
#pragma unroll
    for (int kk = 0; kk < 4; kk++) {
      h4 af[4], bf[4];
#pragma unroll
      for (int m = 0; m < 4; m++)
        af[m] = *reinterpret_cast<h4*>(&la[wr + m * 16 + r16][kk * 16 + 4 * g]);
#pragma unroll
      for (int n = 0; n < 4; n++)
        bf[n] = *reinterpret_cast<h4*>(&lb[wc + n * 16 + r16][kk * 16 + 4 * g]);
#pragma unroll
      for (int m = 0; m < 4; m++)
#pragma unroll
        for (int n = 0; n < 4; n++)
          acc[m][n] = __builtin_amdgcn_mfma_f32_16x16x16f16(af[m], bf[n], acc[m][n], 0, 0, 0);
    }
    __syncthreads();
  }

  // epilogue: D frag layout col = r16, row = 4g + reg
#pragma unroll
  for (int n = 0; n < 4; n++) {
    int gc = n0 + wc + n * 16 + r16;
    float bv = bias[gc];
#pragma unroll
    for (int m = 0; m < 4; m++) {
#pragma unroll
      for (int r = 0; r < 4; r++) {
        int gr = m0 + wr + m * 16 + 4 * g + r;
        float vv = acc[m][n][r] + bv;
        if (OUTF32)
          reinterpret_cast<float*>(out)[(size_t)gr * EMBED + gc] = vv;
        else
          reinterpret_cast<_Float16*>(out)[(size_t)gr * EMBED + gc] = (_Float16)vv;
      }
    }
  }
}

// ---------------- V transpose: [B,S,H*64] -> per-head [B*H, 64, S] ----------
__global__ __launch_bounds__(256) void transpose_v(const _Float16* __restrict__ Vp,
                                                   _Float16* __restrict__ Vt) {
  __shared__ _Float16 tile[64][72];
  const int s0 = blockIdx.x * 64;
  const int bh = blockIdx.y;
  const int b = bh >> 4, h = bh & 15;
  const int t = threadIdx.x;
#pragma unroll
  for (int it = 0; it < 2; it++) {
    int c = t + it * 256;
    int r = c >> 3, c8 = (c & 7) * 8;
    *reinterpret_cast<float4*>(&tile[r][c8]) =
        *reinterpret_cast<const float4*>(Vp + ((size_t)b * SS + s0 + r) * EMBED + h * HD + c8);
  }
  __syncthreads();
#pragma unroll
  for (int it = 0; it < 2; it++) {
    int c = t + it * 256;
    int d = c >> 3, s8 = (c & 7) * 8;
    h4 lo = {tile[s8 + 0][d], tile[s8 + 1][d], tile[s8 + 2][d], tile[s8 + 3][d]};
    h4 hi = {tile[s8 + 4][d], tile[s8 + 5][d], tile[s8 + 6][d], tile[s8 + 7][d]};
    _Float16* dst = Vt + ((size_t)bh * HD + d) * SS + s0 + s8;
    *reinterpret_cast<h4*>(dst) = lo;
    *reinterpret_cast<h4*>(dst + 4) = hi;
  }
}

// ---------------- fused attention -------------------------------------------
// Grid: (SQ/64, B*H). Block 256 = 4 waves; wave w owns q rows [qt*64+16w, +16).
// Swapped QK^T: S^T = mfma(K_frag, Q_frag) -> lane holds S[key=4g+reg][q=r16].
// Pass 1: online row max+sum. Pass 2: recompute S (identical op order), write
// attn = exp2((z-m)*log2e)/l as float4, PV-accumulate via 16x16x16 MFMA whose
// A-frag (P[q=r16][key=4g+j]) exactly matches the S^T C-frag layout.
__global__ __launch_bounds__(256, 2) void attn_fused(const _Float16* __restrict__ Q,
                                                     const _Float16* __restrict__ K,
                                                     const _Float16* __restrict__ Vt,
                                                     float* __restrict__ attn_out,
                                                     _Float16* __restrict__ Oh) {
  __shared__ _Float16 lk[64][72];
  __shared__ _Float16 lv[64][72];
  const int t = threadIdx.x;
  const int lane = t & 63;
  const int w = t >> 6;
  const int g = lane >> 4, r16 = lane & 15;
  const int qt = blockIdx.x;
  const int bh = blockIdx.y;
  const int b = bh >> 4, h = bh & 15;
  const int qrow = qt * 64 + w * 16 + r16;

  const float SCALE = 0.125f;            // 1/sqrt(64)
  const float L2E = 1.44269504088896f;   // log2(e)

  // hoist Q fragments (B-operand: col=q=r16, k=d=kk*16+4g+j)
  h4 qf[4];
  const _Float16* qptr = Q + ((size_t)b * SS + qrow) * EMBED + h * HD;
#pragma unroll
  for (int kk = 0; kk < 4; kk++)
    qf[kk] = *reinterpret_cast<const h4*>(qptr + kk * 16 + 4 * g);

  const _Float16* kbase = K + (size_t)b * SS * EMBED + h * HD;
  const _Float16* vtbase = Vt + (size_t)bh * HD * SS;

  float m_run = -INFINITY, l_run = 0.0f;

  // ---- pass 1: row max and sum over all 2048 keys ----
  for (int kb = 0; kb < 32; kb++) {
#pragma unroll
    for (int it = 0; it < 2; it++) {
      int c = t + it * 256;
      int row = c >> 3, col8 = (c & 7) * 8;
      *reinterpret_cast<float4*>(&lk[row][col8]) =
          *reinterpret_cast<const float4*>(kbase + (size_t)(kb * 64 + row) * EMBED + col8);
    }
    __syncthreads();
    float sv[16];
#pragma unroll
    for (int kf = 0; kf < 4; kf++) {
      f4 sf = {0.f, 0.f, 0.f, 0.f};
#pragma unroll
      for (int kk = 0; kk < 4; kk++) {
        h4 af = *reinterpret_cast<h4*>(&lk[kf * 16 + r16][kk * 16 + 4 * g]);
        sf = __builtin_amdgcn_mfma_f32_16x16x16f16(af, qf[kk], sf, 0, 0, 0);
      }
#pragma unroll
      for (int r = 0; r < 4; r++) sv[kf * 4 + r] = sf[r] * SCALE;
    }
    __syncthreads();
    float bm = sv[0];
#pragma unroll
    for (int i = 1; i < 16; i++) bm = fmaxf(bm, sv[i]);
    bm = fmaxf(bm, __shfl_xor(bm, 16, 64));
    bm = fmaxf(bm, __shfl_xor(bm, 32, 64));
    float mn = fmaxf(m_run, bm);
    float s = 0.f;
#pragma unroll
    for (int i = 0; i < 16; i++) s += fexp2((sv[i] - mn) * L2E);
    s += __shfl_xor(s, 16, 64);
    s += __shfl_xor(s, 32, 64);
    l_run = l_run * fexp2((m_run - mn) * L2E) + s;
    m_run = mn;
  }

  // ---- pass 2: recompute, write normalized attn, accumulate PV ----
  const float rinv = 1.0f / l_run;
  f4 oacc[4] = {};
  float* arow = attn_out + ((size_t)bh * SS + qrow) * SS;

  for (int kb = 0; kb < 32; kb++) {
#pragma unroll
    for (int it = 0; it < 2; it++) {
      int c = t + it * 256;
      int row = c >> 3, col8 = (c & 7) * 8;
      *reinterpret_cast<float4*>(&lk[row][col8]) =
          *reinterpret_cast<const float4*>(kbase + (size_t)(kb * 64 + row) * EMBED + col8);
      *reinterpret_cast<float4*>(&lv[row][col8]) =
          *reinterpret_cast<const float4*>(vtbase + (size_t)row * SS + kb * 64 + col8);
    }
    __syncthreads();
#pragma unroll
    for (int kf = 0; kf < 4; kf++) {
      f4 sf = {0.f, 0.f, 0.f, 0.f};
#pragma unroll
      for (int kk = 0; kk < 4; kk++) {
        h4 af = *reinterpret_cast<h4*>(&lk[kf * 16 + r16][kk * 16 + 4 * g]);
        sf = __builtin_amdgcn_mfma_f32_16x16x16f16(af, qf[kk], sf, 0, 0, 0);
      }
      float a0 = fexp2((sf[0] * SCALE - m_run) * L2E) * rinv;
      float a1 = fexp2((sf[1] * SCALE - m_run) * L2E) * rinv;
      float a2 = fexp2((sf[2] * SCALE - m_run) * L2E) * rinv;
      float a3 = fexp2((sf[3] * SCALE - m_run) * L2E) * rinv;
      float4 st = {a0, a1, a2, a3};
      *reinterpret_cast<float4*>(arow + kb * 64 + kf * 16 + 4 * g) = st;
      h4 pa = {(_Float16)a0, (_Float16)a1, (_Float16)a2, (_Float16)a3};
#pragma unroll
      for (int dt = 0; dt < 4; dt++) {
        h4 bf = *reinterpret_cast<h4*>(&lv[dt * 16 + r16][kf * 16 + 4 * g]);
        oacc[dt] = __builtin_amdgcn_mfma_f32_16x16x16f16(pa, bf, oacc[dt], 0, 0, 0);
      }
    }
    __syncthreads();
  }

  // write O (fp16) to [B,S,EMBED] for the final projection
  const int orow0 = qt * 64 + w * 16;
#pragma unroll
  for (int dt = 0; dt < 4; dt++) {
#pragma unroll
    for (int r = 0; r < 4; r++) {
      Oh[((size_t)b * SS + orow0 + 4 * g + r) * EMBED + h * HD + dt * 16 + r16] =
          (_Float16)oacc[dt][r];
    }
  }
}

// ---------------------------------------------------------------------------
extern "C" void kernel_launch(void* const* d_in, const int* in_sizes, int n_in,
                              void* d_out, int out_size, void* d_ws, size_t ws_size,
                              hipStream_t stream) {
  const float* q  = (const float*)d_in[0];
  const float* k  = (const float*)d_in[1];
  const float* v  = (const float*)d_in[2];
  const float* Wq = (const float*)d_in[3];
  const float* bq = (const float*)d_in[4];
  const float* Wk = (const float*)d_in[5];
  const float* bk = (const float*)d_in[6];
  const float* Wv = (const float*)d_in[7];
  const float* bv = (const float*)d_in[8];
  const float* Wo = (const float*)d_in[9];
  const float* bo = (const float*)d_in[10];

  const size_t NW = (size_t)EMBED * EMBED;   // 1,048,576
  const size_t NX = (size_t)MROWS * EMBED;   // 8,388,608

  // workspace layout (halves). Total = (4*NW + 6*NX)*2 B = ~109 MB.
  if (ws_size < (4 * NW + 6 * NX) * sizeof(_Float16)) return;  // loud failure
  _Float16* ws  = (_Float16*)d_ws;
  _Float16* wqh = ws;
  _Float16* wkh = wqh + NW;
  _Float16* wvh = wkh + NW;
  _Float16* woh = wvh + NW;
  _Float16* qh  = woh + NW;
  _Float16* kh  = qh + NX;
  _Float16* vh  = kh + NX;
  _Float16* Qh  = vh + NX;
  _Float16* Kh  = Qh + NX;
  _Float16* Vph = Kh + NX;
  _Float16* VtA = qh;  // alias: qh dead after Q projection
  _Float16* OhA = kh;  // alias: kh dead after K projection

  float* xout = (float*)d_out;
  float* attn = xout + NX;

  // casts
  {
    dim3 blk(256);
    cast_f32_f16<<<dim3((NW / 4 + 255) / 256), blk, 0, stream>>>(Wq, wqh, (int)NW);
    cast_f32_f16<<<dim3((NW / 4 + 255) / 256), blk, 0, stream>>>(Wk, wkh, (int)NW);
    cast_f32_f16<<<dim3((NW / 4 + 255) / 256), blk, 0, stream>>>(Wv, wvh, (int)NW);
    cast_f32_f16<<<dim3((NW / 4 + 255) / 256), blk, 0, stream>>>(Wo, woh, (int)NW);
    cast_f32_f16<<<dim3((NX / 4 + 255) / 256), blk, 0, stream>>>(q, qh, (int)NX);
    cast_f32_f16<<<dim3((NX / 4 + 255) / 256), blk, 0, stream>>>(k, kh, (int)NX);
    cast_f32_f16<<<dim3((NX / 4 + 255) / 256), blk, 0, stream>>>(v, vh, (int)NX);
  }

  dim3 ggrid(MROWS / 128, EMBED / 128), gblk(256);
  gemm_bias<0><<<ggrid, gblk, 0, stream>>>(qh, wqh, bq, (void*)Qh);
  gemm_bias<0><<<ggrid, gblk, 0, stream>>>(kh, wkh, bk, (void*)Kh);
  gemm_bias<0><<<ggrid, gblk, 0, stream>>>(vh, wvh, bv, (void*)Vph);

  transpose_v<<<dim3(SS / 64, BB * HEADS), dim3(256), 0, stream>>>(Vph, VtA);

  attn_fused<<<dim3(SS / 64, BB * HEADS), dim3(256), 0, stream>>>(Qh, Kh, VtA, attn, OhA);

  gemm_bias<1><<<ggrid, gblk, 0, stream>>>(OhA, woh, bo, (void*)xout);
}

// Round 3
// 516.281 us; speedup vs baseline: 1.4180x; 1.4180x over previous
//
#include <hip/hip_runtime.h>
#include <hip/hip_bf16.h>

// ---------------------------------------------------------------------------
// CustomMultiheadAttention on MI355X (gfx950)
//   x = softmax((q Wq^T + bq)(k Wk^T + bk)^T / sqrt(64)) (v Wv^T + bv) Wo^T + bo
// Outputs (concat, fp32): x [4,2048,1024], attn [4,16,2048,2048]
//
// Round-2b: 16x16x32 f16 MFMA (2x rate; A/B use consistent k-mapping so the
// layout ambiguity cancels), global_load_lds width-16 staging with XOR
// swizzle (linear LDS dest + inverse-swizzled global source + swizzled
// ds_read — rule #21), nontemporal attn stores (ext_vector f4, not HIP float4).
// ---------------------------------------------------------------------------

typedef _Float16 h4 __attribute__((ext_vector_type(4)));
typedef _Float16 h8 __attribute__((ext_vector_type(8)));
typedef float f4 __attribute__((ext_vector_type(4)));

#define EMBED 1024
#define HEADS 16
#define HD 64
#define BB 4
#define SS 2048
#define MROWS (BB * SS) // 8192

#define GLD(src, dst)                                                                  \
  __builtin_amdgcn_global_load_lds((const __attribute__((address_space(1))) void*)(src), \
                                   (__attribute__((address_space(3))) void*)(dst), 16, 0, 0)

__device__ inline float fexp2(float x) {
  float r;
  asm("v_exp_f32 %0, %1" : "=v"(r) : "v"(x));
  return r;
}

// ---------------- cast fp32 -> fp16 (vectorized) ----------------
__global__ __launch_bounds__(256) void cast_f32_f16(const float* __restrict__ in,
                                                    _Float16* __restrict__ out, int n) {
  int i = (blockIdx.x * 256 + threadIdx.x) * 4;
  if (i < n) {
    float4 v = *reinterpret_cast<const float4*>(in + i);
    h4 o = {(_Float16)v.x, (_Float16)v.y, (_Float16)v.z, (_Float16)v.w};
    *reinterpret_cast<h4*>(out + i) = o;
  }
}

// ---------------- GEMM: out[m][n] = sum_k A[m][k] * W[n][k] + bias[n] -------
// 128x128 tile, BK=64, 4 waves (each 64x64), 16x16x32 f16 MFMA.
// LDS: linear [128][64] halves (128B rows), global_load_lds w16 staging.
// Swizzle: physical byte holds logical col (pc ^ ((row&7)<<4)); reads apply
// the same XOR. Involution, both-sides consistent.
template <int OUTF32>
__global__ __launch_bounds__(256, 2) void gemm_bias(const _Float16* __restrict__ A,
                                                    const _Float16* __restrict__ W,
                                                    const float* __restrict__ bias,
                                                    void* __restrict__ out) {
  __shared__ char smem[32768];
  char* la = smem;
  char* lb = smem + 16384;
  const int t = threadIdx.x;
  const int lane = t & 63;
  const int w = t >> 6;
  const int g = lane >> 4, r16 = lane & 15;
  const int wr = (w >> 1) * 64, wc = (w & 1) * 64;
  const int m0 = blockIdx.x * 128, n0 = blockIdx.y * 128;
  const int p_in_wave = (w << 10) + (lane << 4);

  const char* Ab = (const char*)A;
  const char* Wb = (const char*)W;

  f4 acc[4][4] = {};

  for (int kt = 0; kt < EMBED; kt += 64) {
#pragma unroll
    for (int c = 0; c < 4; c++) {
      int p0 = c * 4096 + p_in_wave;
      int row = p0 >> 7;
      int scol = (p0 & 127) ^ ((row & 7) << 4);
      GLD(Ab + ((size_t)(m0 + row) * EMBED + kt) * 2 + scol, la + c * 4096 + (w << 10));
      GLD(Wb + ((size_t)(n0 + row) * EMBED + kt) * 2 + scol, lb + c * 4096 + (w << 10));
    }
    __syncthreads();
    const int sw = (r16 & 7) << 4;
#pragma unroll
    for (int kk = 0; kk < 2; kk++) {
      h8 af[4], bf[4];
#pragma unroll
      for (int m = 0; m < 4; m++)
        af[m] = *(const h8*)(la + (wr + m * 16 + r16) * 128 + ((kk * 64 + 16 * g) ^ sw));
#pragma unroll
      for (int n = 0; n < 4; n++)
        bf[n] = *(const h8*)(lb + (wc + n * 16 + r16) * 128 + ((kk * 64 + 16 * g) ^ sw));
#pragma unroll
      for (int m = 0; m < 4; m++)
#pragma unroll
        for (int n = 0; n < 4; n++)
          acc[m][n] = __builtin_amdgcn_mfma_f32_16x16x32_f16(af[m], bf[n], acc[m][n], 0, 0, 0);
    }
    __syncthreads();
  }

  // epilogue: D frag layout col = r16, row = 4g + reg
#pragma unroll
  for (int n = 0; n < 4; n++) {
    int gc = n0 + wc + n * 16 + r16;
    float bv = bias[gc];
#pragma unroll
    for (int m = 0; m < 4; m++) {
#pragma unroll
      for (int r = 0; r < 4; r++) {
        int gr = m0 + wr + m * 16 + 4 * g + r;
        float vv = acc[m][n][r] + bv;
        if (OUTF32)
          reinterpret_cast<float*>(out)[(size_t)gr * EMBED + gc] = vv;
        else
          reinterpret_cast<_Float16*>(out)[(size_t)gr * EMBED + gc] = (_Float16)vv;
      }
    }
  }
}

// ---------------- V transpose: [B,S,H*64] -> per-head [B*H, 64, S] ----------
__global__ __launch_bounds__(256) void transpose_v(const _Float16* __restrict__ Vp,
                                                   _Float16* __restrict__ Vt) {
  __shared__ _Float16 tile[64][72];
  const int s0 = blockIdx.x * 64;
  const int bh = blockIdx.y;
  const int b = bh >> 4, h = bh & 15;
  const int t = threadIdx.x;
#pragma unroll
  for (int it = 0; it < 2; it++) {
    int c = t + it * 256;
    int r = c >> 3, c8 = (c & 7) * 8;
    *reinterpret_cast<float4*>(&tile[r][c8]) =
        *reinterpret_cast<const float4*>(Vp + ((size_t)b * SS + s0 + r) * EMBED + h * HD + c8);
  }
  __syncthreads();
#pragma unroll
  for (int it = 0; it < 2; it++) {
    int c = t + it * 256;
    int d = c >> 3, s8 = (c & 7) * 8;
    h4 lo = {tile[s8 + 0][d], tile[s8 + 1][d], tile[s8 + 2][d], tile[s8 + 3][d]};
    h4 hi = {tile[s8 + 4][d], tile[s8 + 5][d], tile[s8 + 6][d], tile[s8 + 7][d]};
    _Float16* dst = Vt + ((size_t)bh * HD + d) * SS + s0 + s8;
    *reinterpret_cast<h4*>(dst) = lo;
    *reinterpret_cast<h4*>(dst + 4) = hi;
  }
}

// ---------------- fused attention -------------------------------------------
// Grid: (SQ/64, B*H). Block 256 = 4 waves; wave w owns q rows [qt*64+16w, +16).
// Swapped QK^T (16x16x32 over d): S^T frag -> lane holds S[key=4g+r][q=r16].
// Pass 1: online row max+sum. Pass 2: recompute S (identical MFMA chain),
// write attn (nontemporal f4), PV via 16x16x32 whose A-frag = two S^T
// C-frags concatenated (k-mapping {4g+j, 16+4g+j}, consistent with B).
__global__ __launch_bounds__(256, 2) void attn_fused(const _Float16* __restrict__ Q,
                                                     const _Float16* __restrict__ K,
                                                     const _Float16* __restrict__ Vt,
                                                     float* __restrict__ attn_out,
                                                     _Float16* __restrict__ Oh) {
  __shared__ char smem[16384];
  char* lk = smem;
  char* lv = smem + 8192;
  const int t = threadIdx.x;
  const int lane = t & 63;
  const int w = t >> 6;
  const int g = lane >> 4, r16 = lane & 15;
  const int qt = blockIdx.x;
  const int bh = blockIdx.y;
  const int b = bh >> 4, h = bh & 15;
  const int qrow = qt * 64 + w * 16 + r16;
  const int p_in_wave = (w << 10) + (lane << 4);
  const int sw = (r16 & 7) << 4;

  const float SCALE = 0.125f;           // 1/sqrt(64)
  const float L2E = 1.44269504088896f;  // log2(e)

  // hoist Q fragments (B-operand: col=q=r16, k = kk*32 + 8g + j)
  h8 qf[2];
  const _Float16* qptr = Q + ((size_t)b * SS + qrow) * EMBED + h * HD;
#pragma unroll
  for (int kk = 0; kk < 2; kk++)
    qf[kk] = *reinterpret_cast<const h8*>(qptr + kk * 32 + 8 * g);

  const char* kbase = (const char*)K + ((size_t)b * SS * EMBED + h * HD) * 2;
  const char* vtbase = (const char*)Vt + (size_t)bh * HD * SS * 2;

  float m_run = -INFINITY, l_run = 0.0f;

  // ---- pass 1: row max and sum over all 2048 keys ----
  for (int kb = 0; kb < 32; kb++) {
#pragma unroll
    for (int c = 0; c < 2; c++) {
      int p0 = c * 4096 + p_in_wave;
      int row = p0 >> 7;
      int scol = (p0 & 127) ^ ((row & 7) << 4);
      GLD(kbase + (size_t)(kb * 64 + row) * 2048 + scol, lk + c * 4096 + (w << 10));
    }
    __syncthreads();
    float sv[16];
#pragma unroll
    for (int kf = 0; kf < 4; kf++) {
      f4 sf = {0.f, 0.f, 0.f, 0.f};
#pragma unroll
      for (int kk = 0; kk < 2; kk++) {
        h8 af = *(const h8*)(lk + (kf * 16 + r16) * 128 + ((kk * 64 + 16 * g) ^ sw));
        sf = __builtin_amdgcn_mfma_f32_16x16x32_f16(af, qf[kk], sf, 0, 0, 0);
      }
#pragma unroll
      for (int r = 0; r < 4; r++) sv[kf * 4 + r] = sf[r] * SCALE;
    }
    __syncthreads();
    float bm = sv[0];
#pragma unroll
    for (int i = 1; i < 16; i++) bm = fmaxf(bm, sv[i]);
    bm = fmaxf(bm, __shfl_xor(bm, 16, 64));
    bm = fmaxf(bm, __shfl_xor(bm, 32, 64));
    float mn = fmaxf(m_run, bm);
    float s = 0.f;
#pragma unroll
    for (int i = 0; i < 16; i++) s += fexp2((sv[i] - mn) * L2E);
    s += __shfl_xor(s, 16, 64);
    s += __shfl_xor(s, 32, 64);
    l_run = l_run * fexp2((m_run - mn) * L2E) + s;
    m_run = mn;
  }

  // ---- pass 2: recompute, write normalized attn, accumulate PV ----
  const float rinv = 1.0f / l_run;
  f4 oacc[4] = {};
  float* arow = attn_out + ((size_t)bh * SS + qrow) * SS;

  for (int kb = 0; kb < 32; kb++) {
#pragma unroll
    for (int c = 0; c < 2; c++) {
      int p0 = c * 4096 + p_in_wave;
      int row = p0 >> 7;
      int scol = (p0 & 127) ^ ((row & 7) << 4);
      GLD(kbase + (size_t)(kb * 64 + row) * 2048 + scol, lk + c * 4096 + (w << 10));
      GLD(vtbase + (size_t)row * 4096 + kb * 128 + scol, lv + c * 4096 + (w << 10));
    }
    __syncthreads();
    h4 pa[4];
#pragma unroll
    for (int kf = 0; kf < 4; kf++) {
      f4 sf = {0.f, 0.f, 0.f, 0.f};
#pragma unroll
      for (int kk = 0; kk < 2; kk++) {
        h8 af = *(const h8*)(lk + (kf * 16 + r16) * 128 + ((kk * 64 + 16 * g) ^ sw));
        sf = __builtin_amdgcn_mfma_f32_16x16x32_f16(af, qf[kk], sf, 0, 0, 0);
      }
      float a0 = fexp2((sf[0] * SCALE - m_run) * L2E) * rinv;
      float a1 = fexp2((sf[1] * SCALE - m_run) * L2E) * rinv;
      float a2 = fexp2((sf[2] * SCALE - m_run) * L2E) * rinv;
      float a3 = fexp2((sf[3] * SCALE - m_run) * L2E) * rinv;
      f4 st = {a0, a1, a2, a3};
      __builtin_nontemporal_store(st, reinterpret_cast<f4*>(arow + kb * 64 + kf * 16 + 4 * g));
      pa[kf] = h4{(_Float16)a0, (_Float16)a1, (_Float16)a2, (_Float16)a3};
    }
    // PV: key block of 32 per MFMA; A k-mapping j<4 -> 4g+j, j>=4 -> 16+4g+j.
#pragma unroll
    for (int kf2 = 0; kf2 < 2; kf2++) {
      h8 pa8 = __builtin_shufflevector(pa[2 * kf2], pa[2 * kf2 + 1], 0, 1, 2, 3, 4, 5, 6, 7);
#pragma unroll
      for (int dt = 0; dt < 4; dt++) {
        const char* vrow = lv + (dt * 16 + r16) * 128;
        h4 blo = *(const h4*)(vrow + ((kf2 * 64 + 8 * g) ^ sw));
        h4 bhi = *(const h4*)(vrow + ((kf2 * 64 + 32 + 8 * g) ^ sw));
        h8 bf8 = __builtin_shufflevector(blo, bhi, 0, 1, 2, 3, 4, 5, 6, 7);
        oacc[dt] = __builtin_amdgcn_mfma_f32_16x16x32_f16(pa8, bf8, oacc[dt], 0, 0, 0);
      }
    }
    __syncthreads();
  }

  // write O (fp16) to [B,S,EMBED] for the final projection
  const int orow0 = qt * 64 + w * 16;
#pragma unroll
  for (int dt = 0; dt < 4; dt++) {
#pragma unroll
    for (int r = 0; r < 4; r++) {
      Oh[((size_t)b * SS + orow0 + 4 * g + r) * EMBED + h * HD + dt * 16 + r16] =
          (_Float16)oacc[dt][r];
    }
  }
}

// ---------------------------------------------------------------------------
extern "C" void kernel_launch(void* const* d_in, const int* in_sizes, int n_in,
                              void* d_out, int out_size, void* d_ws, size_t ws_size,
                              hipStream_t stream) {
  const float* q  = (const float*)d_in[0];
  const float* k  = (const float*)d_in[1];
  const float* v  = (const float*)d_in[2];
  const float* Wq = (const float*)d_in[3];
  const float* bq = (const float*)d_in[4];
  const float* Wk = (const float*)d_in[5];
  const float* bk = (const float*)d_in[6];
  const float* Wv = (const float*)d_in[7];
  const float* bv = (const float*)d_in[8];
  const float* Wo = (const float*)d_in[9];
  const float* bo = (const float*)d_in[10];

  const size_t NW = (size_t)EMBED * EMBED;   // 1,048,576
  const size_t NX = (size_t)MROWS * EMBED;   // 8,388,608

  // workspace layout (halves). Total = (4*NW + 6*NX)*2 B = ~109 MB.
  if (ws_size < (4 * NW + 6 * NX) * sizeof(_Float16)) return;  // loud failure
  _Float16* ws  = (_Float16*)d_ws;
  _Float16* wqh = ws;
  _Float16* wkh = wqh + NW;
  _Float16* wvh = wkh + NW;
  _Float16* woh = wvh + NW;
  _Float16* qh  = woh + NW;
  _Float16* kh  = qh + NX;
  _Float16* vh  = kh + NX;
  _Float16* Qh  = vh + NX;
  _Float16* Kh  = Qh + NX;
  _Float16* Vph = Kh + NX;
  _Float16* VtA = qh;  // alias: qh dead after Q projection
  _Float16* OhA = kh;  // alias: kh dead after K projection

  float* xout = (float*)d_out;
  float* attn = xout + NX;

  // casts
  {
    dim3 blk(256);
    cast_f32_f16<<<dim3((NW / 4 + 255) / 256), blk, 0, stream>>>(Wq, wqh, (int)NW);
    cast_f32_f16<<<dim3((NW / 4 + 255) / 256), blk, 0, stream>>>(Wk, wkh, (int)NW);
    cast_f32_f16<<<dim3((NW / 4 + 255) / 256), blk, 0, stream>>>(Wv, wvh, (int)NW);
    cast_f32_f16<<<dim3((NW / 4 + 255) / 256), blk, 0, stream>>>(Wo, woh, (int)NW);
    cast_f32_f16<<<dim3((NX / 4 + 255) / 256), blk, 0, stream>>>(q, qh, (int)NX);
    cast_f32_f16<<<dim3((NX / 4 + 255) / 256), blk, 0, stream>>>(k, kh, (int)NX);
    cast_f32_f16<<<dim3((NX / 4 + 255) / 256), blk, 0, stream>>>(v, vh, (int)NX);
  }

  dim3 ggrid(MROWS / 128, EMBED / 128), gblk(256);
  gemm_bias<0><<<ggrid, gblk, 0, stream>>>(qh, wqh, bq, (void*)Qh);
  gemm_bias<0><<<ggrid, gblk, 0, stream>>>(kh, wkh, bk, (void*)Kh);
  gemm_bias<0><<<ggrid, gblk, 0, stream>>>(vh, wvh, bv, (void*)Vph);

  transpose_v<<<dim3(SS / 64, BB * HEADS), dim3(256), 0, stream>>>(Vph, VtA);

  attn_fused<<<dim3(SS / 64, BB * HEADS), dim3(256), 0, stream>>>(Qh, Kh, VtA, attn, OhA);

  gemm_bias<1><<<ggrid, gblk, 0, stream>>>(OhA, woh, bo, (void*)xout);
}

// Round 5
// 501.273 us; speedup vs baseline: 1.4605x; 1.0299x over previous
//
#include <hip/hip_runtime.h>
#include <hip/hip_bf16.h>

// ---------------------------------------------------------------------------
// CustomMultiheadAttention on MI355X (gfx950)
//   x = softmax((q Wq^T + bq)(k Wk^T + bk)^T / sqrt(64)) (v Wv^T + bv) Wo^T + bo
// Outputs (concat, fp32): x [4,2048,1024], attn [4,16,2048,2048]
//
// Round-4: attn double-buffered staging (T3 minimum 2-phase: STAGE(next)
// before compute(cur), ONE barrier/iter), s_setprio around attn MFMA (T5),
// QKV projections fused into one grid.z=3 launch, casts fused 7->2 launches.
// LDS double-buffer selected by integer offset (no LDS-pointer arrays —
// addrspacecast in static initializers doesn't compile).
// ---------------------------------------------------------------------------

typedef _Float16 h4 __attribute__((ext_vector_type(4)));
typedef _Float16 h8 __attribute__((ext_vector_type(8)));
typedef float f4 __attribute__((ext_vector_type(4)));

#define EMBED 1024
#define HEADS 16
#define HD 64
#define BB 4
#define SS 2048
#define MROWS (BB * SS) // 8192

#define GLD(src, dst)                                                                  \
  __builtin_amdgcn_global_load_lds((const __attribute__((address_space(1))) void*)(src), \
                                   (__attribute__((address_space(3))) void*)(dst), 16, 0, 0)

__device__ inline float fexp2(float x) {
  float r;
  asm("v_exp_f32 %0, %1" : "=v"(r) : "v"(x));
  return r;
}

// ---------------- fused casts fp32 -> fp16 ----------------
__global__ __launch_bounds__(256) void cast3_f32_f16(const float* __restrict__ a,
                                                     const float* __restrict__ b,
                                                     const float* __restrict__ c,
                                                     _Float16* __restrict__ oa,
                                                     _Float16* __restrict__ ob,
                                                     _Float16* __restrict__ oc, int n) {
  const float* in = blockIdx.y == 0 ? a : blockIdx.y == 1 ? b : c;
  _Float16* out = blockIdx.y == 0 ? oa : blockIdx.y == 1 ? ob : oc;
  int i = (blockIdx.x * 256 + threadIdx.x) * 4;
  if (i < n) {
    float4 v = *reinterpret_cast<const float4*>(in + i);
    h4 o = {(_Float16)v.x, (_Float16)v.y, (_Float16)v.z, (_Float16)v.w};
    *reinterpret_cast<h4*>(out + i) = o;
  }
}

__global__ __launch_bounds__(256) void cast4_f32_f16(const float* __restrict__ a,
                                                     const float* __restrict__ b,
                                                     const float* __restrict__ c,
                                                     const float* __restrict__ d,
                                                     _Float16* __restrict__ oa,
                                                     _Float16* __restrict__ ob,
                                                     _Float16* __restrict__ oc,
                                                     _Float16* __restrict__ od, int n) {
  const float* in = blockIdx.y == 0 ? a : blockIdx.y == 1 ? b : blockIdx.y == 2 ? c : d;
  _Float16* out = blockIdx.y == 0 ? oa : blockIdx.y == 1 ? ob : blockIdx.y == 2 ? oc : od;
  int i = (blockIdx.x * 256 + threadIdx.x) * 4;
  if (i < n) {
    float4 v = *reinterpret_cast<const float4*>(in + i);
    h4 o = {(_Float16)v.x, (_Float16)v.y, (_Float16)v.z, (_Float16)v.w};
    *reinterpret_cast<h4*>(out + i) = o;
  }
}

// ---------------- GEMM core: out[m][n] = sum_k A[m][k]*W[n][k] + bias[n] ----
// 128x128 tile, BK=64, 4 waves, 16x16x32 f16 MFMA, global_load_lds w16 with
// XOR swizzle (linear LDS dest + pre-swizzled global source + swizzled read).
template <int OUTF32>
__device__ __forceinline__ void gemm_body(const _Float16* __restrict__ A,
                                          const _Float16* __restrict__ W,
                                          const float* __restrict__ bias,
                                          void* __restrict__ out, char* smem) {
  char* la = smem;
  char* lb = smem + 16384;
  const int t = threadIdx.x;
  const int lane = t & 63;
  const int w = t >> 6;
  const int g = lane >> 4, r16 = lane & 15;
  const int wr = (w >> 1) * 64, wc = (w & 1) * 64;
  const int m0 = blockIdx.x * 128, n0 = blockIdx.y * 128;
  const int p_in_wave = (w << 10) + (lane << 4);

  const char* Ab = (const char*)A;
  const char* Wb = (const char*)W;

  f4 acc[4][4] = {};

  for (int kt = 0; kt < EMBED; kt += 64) {
#pragma unroll
    for (int c = 0; c < 4; c++) {
      int p0 = c * 4096 + p_in_wave;
      int row = p0 >> 7;
      int scol = (p0 & 127) ^ ((row & 7) << 4);
      GLD(Ab + ((size_t)(m0 + row) * EMBED + kt) * 2 + scol, la + c * 4096 + (w << 10));
      GLD(Wb + ((size_t)(n0 + row) * EMBED + kt) * 2 + scol, lb + c * 4096 + (w << 10));
    }
    __syncthreads();
    const int sw = (r16 & 7) << 4;
#pragma unroll
    for (int kk = 0; kk < 2; kk++) {
      h8 af[4], bf[4];
#pragma unroll
      for (int m = 0; m < 4; m++)
        af[m] = *(const h8*)(la + (wr + m * 16 + r16) * 128 + ((kk * 64 + 16 * g) ^ sw));
#pragma unroll
      for (int n = 0; n < 4; n++)
        bf[n] = *(const h8*)(lb + (wc + n * 16 + r16) * 128 + ((kk * 64 + 16 * g) ^ sw));
#pragma unroll
      for (int m = 0; m < 4; m++)
#pragma unroll
        for (int n = 0; n < 4; n++)
          acc[m][n] = __builtin_amdgcn_mfma_f32_16x16x32_f16(af[m], bf[n], acc[m][n], 0, 0, 0);
    }
    __syncthreads();
  }

#pragma unroll
  for (int n = 0; n < 4; n++) {
    int gc = n0 + wc + n * 16 + r16;
    float bv = bias[gc];
#pragma unroll
    for (int m = 0; m < 4; m++) {
#pragma unroll
      for (int r = 0; r < 4; r++) {
        int gr = m0 + wr + m * 16 + 4 * g + r;
        float vv = acc[m][n][r] + bv;
        if (OUTF32)
          reinterpret_cast<float*>(out)[(size_t)gr * EMBED + gc] = vv;
        else
          reinterpret_cast<_Float16*>(out)[(size_t)gr * EMBED + gc] = (_Float16)vv;
      }
    }
  }
}

// QKV projections in one launch: blockIdx.z selects (A, W, bias, out).
__global__ __launch_bounds__(256, 2) void gemm_qkv(const _Float16* qh, const _Float16* kh,
                                                   const _Float16* vh, const _Float16* wq,
                                                   const _Float16* wk, const _Float16* wv,
                                                   const float* bq, const float* bk,
                                                   const float* bv, _Float16* Q, _Float16* K,
                                                   _Float16* V) {
  __shared__ char smem[32768];
  const int z = blockIdx.z;
  const _Float16* A = z == 0 ? qh : z == 1 ? kh : vh;
  const _Float16* W = z == 0 ? wq : z == 1 ? wk : wv;
  const float* bias = z == 0 ? bq : z == 1 ? bk : bv;
  _Float16* out = z == 0 ? Q : z == 1 ? K : V;
  gemm_body<0>(A, W, bias, (void*)out, smem);
}

__global__ __launch_bounds__(256, 2) void gemm_out(const _Float16* __restrict__ A,
                                                   const _Float16* __restrict__ W,
                                                   const float* __restrict__ bias,
                                                   float* __restrict__ out) {
  __shared__ char smem[32768];
  gemm_body<1>(A, W, bias, (void*)out, smem);
}

// ---------------- V transpose: [B,S,H*64] -> per-head [B*H, 64, S] ----------
__global__ __launch_bounds__(256) void transpose_v(const _Float16* __restrict__ Vp,
                                                   _Float16* __restrict__ Vt) {
  __shared__ _Float16 tile[64][72];
  const int s0 = blockIdx.x * 64;
  const int bh = blockIdx.y;
  const int b = bh >> 4, h = bh & 15;
  const int t = threadIdx.x;
#pragma unroll
  for (int it = 0; it < 2; it++) {
    int c = t + it * 256;
    int r = c >> 3, c8 = (c & 7) * 8;
    *reinterpret_cast<float4*>(&tile[r][c8]) =
        *reinterpret_cast<const float4*>(Vp + ((size_t)b * SS + s0 + r) * EMBED + h * HD + c8);
  }
  __syncthreads();
#pragma unroll
  for (int it = 0; it < 2; it++) {
    int c = t + it * 256;
    int d = c >> 3, s8 = (c & 7) * 8;
    h4 lo = {tile[s8 + 0][d], tile[s8 + 1][d], tile[s8 + 2][d], tile[s8 + 3][d]};
    h4 hi = {tile[s8 + 4][d], tile[s8 + 5][d], tile[s8 + 6][d], tile[s8 + 7][d]};
    _Float16* dst = Vt + ((size_t)bh * HD + d) * SS + s0 + s8;
    *reinterpret_cast<h4*>(dst) = lo;
    *reinterpret_cast<h4*>(dst + 4) = hi;
  }
}

// ---------------- fused attention -------------------------------------------
// Grid: (SQ/64, B*H). Block 256 = 4 waves; wave w owns q rows [qt*64+16w,+16).
// Swapped QK^T (16x16x32 over d): lane holds S[key=4g+r][q=r16].
// Both passes double-buffered: STAGE(next) issued before compute(cur), one
// __syncthreads per iteration (drains vmcnt; softmax VALU covers load flight).
// Buffer selection via integer offset (kb&1)*8192 — no LDS-pointer arrays.
__global__ __launch_bounds__(256, 2) void attn_fused(const _Float16* __restrict__ Q,
                                                     const _Float16* __restrict__ K,
                                                     const _Float16* __restrict__ Vt,
                                                     float* __restrict__ attn_out,
                                                     _Float16* __restrict__ Oh) {
  __shared__ char smem[32768];
  const int t = threadIdx.x;
  const int lane = t & 63;
  const int w = t >> 6;
  const int g = lane >> 4, r16 = lane & 15;
  const int qt = blockIdx.x;
  const int bh = blockIdx.y;
  const int b = bh >> 4, h = bh & 15;
  const int qrow = qt * 64 + w * 16 + r16;
  const int p_in_wave = (w << 10) + (lane << 4);
  const int sw = (r16 & 7) << 4;

  const float SCALE = 0.125f;           // 1/sqrt(64)
  const float L2E = 1.44269504088896f;  // log2(e)

  const char* kbase = (const char*)K + ((size_t)b * SS * EMBED + h * HD) * 2;
  const char* vtbase = (const char*)Vt + (size_t)bh * HD * SS * 2;

  // per-lane staging source precompute
  int srow[2], scol[2];
#pragma unroll
  for (int c = 0; c < 2; c++) {
    int p0 = c * 4096 + p_in_wave;
    srow[c] = p0 >> 7;
    scol[c] = (p0 & 127) ^ ((srow[c] & 7) << 4);
  }

  // K buffers at smem+{0,8192}, V buffers at smem+{16384,24576}
#define STAGE_K(boff, kb)                                                              \
  {                                                                                    \
    _Pragma("unroll") for (int c = 0; c < 2; c++)                                      \
        GLD(kbase + (size_t)((kb) * 64 + srow[c]) * 2048 + scol[c],                    \
            smem + (boff) + c * 4096 + (w << 10));                                     \
  }
#define STAGE_V(boff, kb)                                                              \
  {                                                                                    \
    _Pragma("unroll") for (int c = 0; c < 2; c++)                                      \
        GLD(vtbase + (size_t)srow[c] * 4096 + (kb) * 128 + scol[c],                    \
            smem + (boff) + c * 4096 + (w << 10));                                     \
  }

  // hoist Q fragments (B-operand: col=q=r16, k = kk*32 + 8g + j)
  h8 qf[2];
  const _Float16* qptr = Q + ((size_t)b * SS + qrow) * EMBED + h * HD;
#pragma unroll
  for (int kk = 0; kk < 2; kk++)
    qf[kk] = *reinterpret_cast<const h8*>(qptr + kk * 32 + 8 * g);

  float m_run = -INFINITY, l_run = 0.0f;

  // ---- pass 1: online row max + sum over all 2048 keys ----
  STAGE_K(0, 0);
  __syncthreads();
  for (int kb = 0; kb < 32; kb++) {
    const char* cur = smem + (kb & 1) * 8192;
    if (kb < 31) STAGE_K(((kb + 1) & 1) * 8192, kb + 1);
    float sv[16];
    __builtin_amdgcn_s_setprio(1);
#pragma unroll
    for (int kf = 0; kf < 4; kf++) {
      f4 sf = {0.f, 0.f, 0.f, 0.f};
#pragma unroll
      for (int kk = 0; kk < 2; kk++) {
        h8 af = *(const h8*)(cur + (kf * 16 + r16) * 128 + ((kk * 64 + 16 * g) ^ sw));
        sf = __builtin_amdgcn_mfma_f32_16x16x32_f16(af, qf[kk], sf, 0, 0, 0);
      }
#pragma unroll
      for (int r = 0; r < 4; r++) sv[kf * 4 + r] = sf[r] * SCALE;
    }
    __builtin_amdgcn_s_setprio(0);
    float bm = fmaxf(fmaxf(fmaxf(sv[0], sv[1]), fmaxf(sv[2], sv[3])),
                     fmaxf(fmaxf(sv[4], sv[5]), fmaxf(sv[6], sv[7])));
    bm = fmaxf(bm, fmaxf(fmaxf(fmaxf(sv[8], sv[9]), fmaxf(sv[10], sv[11])),
                         fmaxf(fmaxf(sv[12], sv[13]), fmaxf(sv[14], sv[15]))));
    bm = fmaxf(bm, __shfl_xor(bm, 16, 64));
    bm = fmaxf(bm, __shfl_xor(bm, 32, 64));
    float mn = fmaxf(m_run, bm);
    float s = 0.f;
#pragma unroll
    for (int i = 0; i < 16; i++) s += fexp2((sv[i] - mn) * L2E);
    s += __shfl_xor(s, 16, 64);
    s += __shfl_xor(s, 32, 64);
    l_run = l_run * fexp2((m_run - mn) * L2E) + s;
    m_run = mn;
    __syncthreads();
  }

  // ---- pass 2: recompute, write normalized attn, accumulate PV ----
  const float rinv = 1.0f / l_run;
  f4 oacc[4] = {};
  float* arow = attn_out + ((size_t)bh * SS + qrow) * SS;

  STAGE_K(0, 0);
  STAGE_V(16384, 0);
  __syncthreads();
  for (int kb = 0; kb < 32; kb++) {
    const char* ck = smem + (kb & 1) * 8192;
    const char* cv = smem + 16384 + (kb & 1) * 8192;
    if (kb < 31) {
      STAGE_K(((kb + 1) & 1) * 8192, kb + 1);
      STAGE_V(16384 + ((kb + 1) & 1) * 8192, kb + 1);
    }
    h4 pa[4];
    __builtin_amdgcn_s_setprio(1);
#pragma unroll
    for (int kf = 0; kf < 4; kf++) {
      f4 sf = {0.f, 0.f, 0.f, 0.f};
#pragma unroll
      for (int kk = 0; kk < 2; kk++) {
        h8 af = *(const h8*)(ck + (kf * 16 + r16) * 128 + ((kk * 64 + 16 * g) ^ sw));
        sf = __builtin_amdgcn_mfma_f32_16x16x32_f16(af, qf[kk], sf, 0, 0, 0);
      }
      __builtin_amdgcn_s_setprio(0);
      float a0 = fexp2((sf[0] * SCALE - m_run) * L2E) * rinv;
      float a1 = fexp2((sf[1] * SCALE - m_run) * L2E) * rinv;
      float a2 = fexp2((sf[2] * SCALE - m_run) * L2E) * rinv;
      float a3 = fexp2((sf[3] * SCALE - m_run) * L2E) * rinv;
      f4 st = {a0, a1, a2, a3};
      __builtin_nontemporal_store(st, reinterpret_cast<f4*>(arow + kb * 64 + kf * 16 + 4 * g));
      pa[kf] = h4{(_Float16)a0, (_Float16)a1, (_Float16)a2, (_Float16)a3};
      __builtin_amdgcn_s_setprio(1);
    }
    // PV: key block of 32 per MFMA; A k-mapping j<4 -> 4g+j, j>=4 -> 16+4g+j.
#pragma unroll
    for (int kf2 = 0; kf2 < 2; kf2++) {
      h8 pa8 = __builtin_shufflevector(pa[2 * kf2], pa[2 * kf2 + 1], 0, 1, 2, 3, 4, 5, 6, 7);
#pragma unroll
      for (int dt = 0; dt < 4; dt++) {
        const char* vrow = cv + (dt * 16 + r16) * 128;
        h4 blo = *(const h4*)(vrow + ((kf2 * 64 + 8 * g) ^ sw));
        h4 bhi = *(const h4*)(vrow + ((kf2 * 64 + 32 + 8 * g) ^ sw));
        h8 bf8 = __builtin_shufflevector(blo, bhi, 0, 1, 2, 3, 4, 5, 6, 7);
        oacc[dt] = __builtin_amdgcn_mfma_f32_16x16x32_f16(pa8, bf8, oacc[dt], 0, 0, 0);
      }
    }
    __builtin_amdgcn_s_setprio(0);
    __syncthreads();
  }

  // write O (fp16) to [B,S,EMBED] for the final projection
  const int orow0 = qt * 64 + w * 16;
#pragma unroll
  for (int dt = 0; dt < 4; dt++) {
#pragma unroll
    for (int r = 0; r < 4; r++) {
      Oh[((size_t)b * SS + orow0 + 4 * g + r) * EMBED + h * HD + dt * 16 + r16] =
          (_Float16)oacc[dt][r];
    }
  }
#undef STAGE_K
#undef STAGE_V
}

// ---------------------------------------------------------------------------
extern "C" void kernel_launch(void* const* d_in, const int* in_sizes, int n_in,
                              void* d_out, int out_size, void* d_ws, size_t ws_size,
                              hipStream_t stream) {
  const float* q  = (const float*)d_in[0];
  const float* k  = (const float*)d_in[1];
  const float* v  = (const float*)d_in[2];
  const float* Wq = (const float*)d_in[3];
  const float* bq = (const float*)d_in[4];
  const float* Wk = (const float*)d_in[5];
  const float* bk = (const float*)d_in[6];
  const float* Wv = (const float*)d_in[7];
  const float* bv = (const float*)d_in[8];
  const float* Wo = (const float*)d_in[9];
  const float* bo = (const float*)d_in[10];

  const size_t NW = (size_t)EMBED * EMBED;   // 1,048,576
  const size_t NX = (size_t)MROWS * EMBED;   // 8,388,608

  if (ws_size < (4 * NW + 6 * NX) * sizeof(_Float16)) return;  // loud failure
  _Float16* ws  = (_Float16*)d_ws;
  _Float16* wqh = ws;
  _Float16* wkh = wqh + NW;
  _Float16* wvh = wkh + NW;
  _Float16* woh = wvh + NW;
  _Float16* qh  = woh + NW;
  _Float16* kh  = qh + NX;
  _Float16* vh  = kh + NX;
  _Float16* Qh  = vh + NX;
  _Float16* Kh  = Qh + NX;
  _Float16* Vph = Kh + NX;
  _Float16* VtA = qh;  // alias: qh dead after Q projection
  _Float16* OhA = kh;  // alias: kh dead after K projection

  float* xout = (float*)d_out;
  float* attn = xout + NX;

  cast3_f32_f16<<<dim3((NX / 4 + 255) / 256, 3), dim3(256), 0, stream>>>(q, k, v, qh, kh, vh,
                                                                         (int)NX);
  cast4_f32_f16<<<dim3((NW / 4 + 255) / 256, 4), dim3(256), 0, stream>>>(
      Wq, Wk, Wv, Wo, wqh, wkh, wvh, woh, (int)NW);

  dim3 ggrid(MROWS / 128, EMBED / 128), gblk(256);
  gemm_qkv<<<dim3(MROWS / 128, EMBED / 128, 3), gblk, 0, stream>>>(qh, kh, vh, wqh, wkh, wvh,
                                                                   bq, bk, bv, Qh, Kh, Vph);

  transpose_v<<<dim3(SS / 64, BB * HEADS), dim3(256), 0, stream>>>(Vph, VtA);

  attn_fused<<<dim3(SS / 64, BB * HEADS), dim3(256), 0, stream>>>(Qh, Kh, VtA, attn, OhA);

  gemm_out<<<ggrid, gblk, 0, stream>>>(OhA, woh, bo, xout);
}